// Round 4
// baseline (1586.490 us; speedup 1.0000x reference)
//
#include <hip/hip_runtime.h>
#include <hip/hip_bf16.h>

#define NVERT 40962
#define NFACE 81920
#define GRID_V ((NVERT + 3) / 4)      // 10241 blocks, 4 vertices/block (1/wave)
#define GRID_F (NFACE / 4)            // 20480 blocks, 4 faces/block (1/wave)

typedef unsigned int uint;
typedef __attribute__((ext_vector_type(4))) uint  uintx4;
typedef __attribute__((ext_vector_type(4))) float floatx4;
typedef __attribute__((ext_vector_type(8))) short shortx8;

// ---------- bf16 helpers (RNE) ----------
__device__ __forceinline__ uint packbf2(float a, float b) {
  uint ua = __float_as_uint(a); ua = ua + 0x7fffu + ((ua >> 16) & 1u);
  uint ub = __float_as_uint(b); ub = ub + 0x7fffu + ((ub >> 16) & 1u);
  return (ua >> 16) | (ub & 0xffff0000u);
}
__device__ __forceinline__ float2 unpackbf2(uint u) {
  float2 r;
  r.x = __uint_as_float(u << 16);
  r.y = __uint_as_float(u & 0xffff0000u);
  return r;
}
__device__ __forceinline__ short bfr(float x) {
  uint u = __float_as_uint(x);
  u = u + 0x7fffu + ((u >> 16) & 1u);
  return (short)(u >> 16);
}

// bijective XCD swizzle (m204)
__device__ __forceinline__ int swz(int blk, int nwg) {
  int q = nwg >> 3, r = nwg & 7;
  int xcd = blk & 7, idx = blk >> 3;
  return (xcd < r ? xcd * (q + 1) : r * (q + 1) + (xcd - r) * q) + idx;
}

// ---------- K0: transpose x[512,NV] f32 -> xT[NV,256] u32 (bf16x2), permuted --
__global__ __launch_bounds__(256) void k_transpose(const float* __restrict__ x,
                                                   uint* __restrict__ xT) {
  __shared__ float tile[32][33];
  int n0 = blockIdx.x * 32;
  int r0 = blockIdx.y * 32;
  int tx = threadIdx.x & 31;
  int ty = threadIdx.x >> 5;
#pragma unroll
  for (int i = 0; i < 32; i += 8) {
    int n = n0 + tx;
    tile[ty + i][tx] = (n < NVERT)
        ? __builtin_nontemporal_load(&x[(size_t)(r0 + ty + i) * NVERT + n]) : 0.f;
  }
  __syncthreads();
#pragma unroll
  for (int i = 0; i < 32; i += 16) {
    int nl = (threadIdx.x >> 4) + i;
    int u  = threadIdx.x & 15;
    int n  = n0 + nl;
    int ug = 16 * blockIdx.y + u;                       // global word index
    int up = (ug & 3) * 64 + (ug >> 4) * 4 + ((ug >> 2) & 3);
    if (n < NVERT)
      xT[(size_t)n * 256 + up] = packbf2(tile[2 * u][nl], tile[2 * u + 1][nl]);
  }
}

// ---------- K0b: pre-convert coeffs -> bf16 MFMA B-fragments ----------
__global__ __launch_bounds__(256) void k_prepw(const float* __restrict__ coeffs,
                                               short* __restrict__ wsW) {
  int t = threadIdx.x;
  int ks = t >> 6, lane = t & 63;
  int bm = lane & 15, h = lane >> 4;
  const float* wp0 = coeffs + (size_t)bm * 128 + 32 * ks + 8 * h;
  shortx8 f0, f1;
#pragma unroll
  for (int j = 0; j < 8; ++j) {
    f0[j] = bfr(wp0[j]);
    f1[j] = bfr(wp0[16 * 128 + j]);
  }
  *(shortx8*)(wsW + ((size_t)(ks * 2 + 0) * 64 + lane) * 8) = f0;
  *(shortx8*)(wsW + ((size_t)(ks * 2 + 1) * 64 + lane) * 8) = f1;
}

// ---------- K1: one wave per face -> gf[NF][512] (ew | ns), scalarized ------
__global__ __launch_bounds__(256, 6) void k_faces(
    const uint* __restrict__ xT,
    const int* __restrict__ Gc, const float* __restrict__ Gv,
    const float* __restrict__ EW, const float* __restrict__ NS,
    uint* __restrict__ gf) {
  const int t = threadIdx.x, lane = t & 63;
  const int f = __builtin_amdgcn_readfirstlane(swz(blockIdx.x, GRID_F) * 4 + (t >> 6));
  const int voff = 4 * lane;

  float ea[4][2], sa[4][2];
#pragma unroll
  for (int ks = 0; ks < 4; ++ks) {
    ea[ks][0] = 0.f; ea[ks][1] = 0.f;
    sa[ks][0] = 0.f; sa[ks][1] = 0.f;
  }

#pragma unroll
  for (int comp = 0; comp < 3; ++comp) {
    const int base = comp * (3 * NFACE) + 3 * f;
    const float ewc = EW[3 * f + comp];      // scalar loads (uniform)
    const float nsc = NS[3 * f + comp];
#pragma unroll
    for (int j = 0; j < 3; ++j) {
      const int col = Gc[base + j];          // scalar load
      const float v = Gv[base + j];
      const float ve = v * ewc, vn = v * nsc;
      uintx4 g = *(const uintx4*)(xT + (size_t)col * 256 + voff);
#pragma unroll
      for (int ks = 0; ks < 4; ++ks) {
        float2 p = unpackbf2(g[ks]);
        ea[ks][0] = fmaf(ve, p.x, ea[ks][0]); ea[ks][1] = fmaf(ve, p.y, ea[ks][1]);
        sa[ks][0] = fmaf(vn, p.x, sa[ks][0]); sa[ks][1] = fmaf(vn, p.y, sa[ks][1]);
      }
    }
  }
  uintx4 we, wn;
#pragma unroll
  for (int ks = 0; ks < 4; ++ks) {
    we[ks] = packbf2(ea[ks][0], ea[ks][1]);
    wn[ks] = packbf2(sa[ks][0], sa[ks][1]);
  }
  uint* op = gf + (size_t)f * 512 + voff;
  *(uintx4*)op         = we;
  *(uintx4*)(op + 256) = wn;
}

// ---------- K2: one wave per vertex, scalarized indices, MFMA channel mix ----
__global__ __launch_bounds__(256, 6) void k_verts(
    const uint* __restrict__ xT,
    const int* __restrict__ Lc, const float* __restrict__ Lv,
    const int* __restrict__ Fc, const float* __restrict__ Fv,
    const uint* __restrict__ gf,
    const short* __restrict__ wsW, const float* __restrict__ bias,
    float* __restrict__ out) {
  const int t = threadIdx.x, lane = t & 63;
  const int n = __builtin_amdgcn_readfirstlane(swz(blockIdx.x, GRID_V) * 4 + (t >> 6));
  if (n >= NVERT) return;
  const int h = lane >> 4, bm = lane & 15;
  const int voff = 4 * lane;

  // identity row
  uintx4 idw = *(const uintx4*)(xT + (size_t)n * 256 + voff);

  float lap[4][2];
#pragma unroll
  for (int ks = 0; ks < 4; ++ks) { lap[ks][0] = 0.f; lap[ks][1] = 0.f; }
#pragma unroll
  for (int j = 0; j < 7; ++j) {
    const int col = Lc[7 * n + j];           // scalar load
    const float v = Lv[7 * n + j];
    uintx4 g = *(const uintx4*)(xT + (size_t)col * 256 + voff);
#pragma unroll
    for (int ks = 0; ks < 4; ++ks) {
      float2 p = unpackbf2(g[ks]);
      lap[ks][0] = fmaf(v, p.x, lap[ks][0]);
      lap[ks][1] = fmaf(v, p.y, lap[ks][1]);
    }
  }

  float ea[4][2], na[4][2];
#pragma unroll
  for (int ks = 0; ks < 4; ++ks) {
    ea[ks][0] = 0.f; ea[ks][1] = 0.f;
    na[ks][0] = 0.f; na[ks][1] = 0.f;
  }
#pragma unroll
  for (int j = 0; j < 6; ++j) {
    const int fc = Fc[6 * n + j];            // scalar load
    const float v = Fv[6 * n + j];
    const uint* rp = gf + (size_t)fc * 512 + voff;
    uintx4 ge = *(const uintx4*)rp;
    uintx4 gn = *(const uintx4*)(rp + 256);
#pragma unroll
    for (int ks = 0; ks < 4; ++ks) {
      float2 a = unpackbf2(ge[ks]);
      float2 b = unpackbf2(gn[ks]);
      ea[ks][0] = fmaf(v, a.x, ea[ks][0]); ea[ks][1] = fmaf(v, a.y, ea[ks][1]);
      na[ks][0] = fmaf(v, b.x, na[ks][0]); na[ks][1] = fmaf(v, b.y, na[ks][1]);
    }
  }

  // A-fragments
  shortx8 afr[4];
#pragma unroll
  for (int ks = 0; ks < 4; ++ks) {
    float2 ip = unpackbf2(idw[ks]);
    shortx8 a;
    a[0] = bfr(ip.x);      a[1] = bfr(lap[ks][0]);
    a[2] = bfr(ea[ks][0]); a[3] = bfr(na[ks][0]);
    a[4] = bfr(ip.y);      a[5] = bfr(lap[ks][1]);
    a[6] = bfr(ea[ks][1]); a[7] = bfr(na[ks][1]);
    afr[ks] = a;
  }

  // MFMA with preconverted B-fragments
  float b0 = bias[bm], b1 = bias[16 + bm];
  floatx4 acc0 = {b0, b0, b0, b0};
  floatx4 acc1 = {b1, b1, b1, b1};
#pragma unroll
  for (int ks = 0; ks < 4; ++ks) {
    shortx8 bf0 = *(const shortx8*)(wsW + ((size_t)(ks * 2 + 0) * 64 + lane) * 8);
    acc0 = __builtin_amdgcn_mfma_f32_16x16x32_bf16(afr[ks], bf0, acc0, 0, 0, 0);
    shortx8 bf1 = *(const shortx8*)(wsW + ((size_t)(ks * 2 + 1) * 64 + lane) * 8);
    acc1 = __builtin_amdgcn_mfma_f32_16x16x32_bf16(afr[ks], bf1, acc1, 0, 0, 0);
  }

  // C/D layout: col = lane&15, row = (lane>>4)*4+reg; out never re-read -> NT
#pragma unroll
  for (int reg = 0; reg < 4; ++reg) {
    int b = h * 4 + reg;
    __builtin_nontemporal_store(acc0[reg], &out[(size_t)(b * 32 + bm) * NVERT + n]);
    __builtin_nontemporal_store(acc1[reg], &out[(size_t)(b * 32 + 16 + bm) * NVERT + n]);
  }
}

extern "C" void kernel_launch(void* const* d_in, const int* in_sizes, int n_in,
                              void* d_out, int out_size, void* d_ws, size_t ws_size,
                              hipStream_t stream) {
  const float* x      = (const float*)d_in[0];
  const int*   Gc     = (const int*)  d_in[2];
  const float* Gv     = (const float*)d_in[3];
  const int*   Lc     = (const int*)  d_in[5];
  const float* Lv     = (const float*)d_in[6];
  const int*   Fc     = (const int*)  d_in[8];
  const float* Fv     = (const float*)d_in[9];
  const float* EW     = (const float*)d_in[10];
  const float* NS     = (const float*)d_in[11];
  const float* coeffs = (const float*)d_in[12];
  const float* bias   = (const float*)d_in[13];
  float* out = (float*)d_out;

  uint* xT  = (uint*)d_ws;                      // NVERT*256 u32
  uint* gf  = xT + (size_t)NVERT * 256;         // NFACE*512 u32 (ew|ns)
  short* wsW = (short*)(gf + (size_t)NFACE * 512);  // 4 KB of B-fragments

  dim3 gT((NVERT + 31) / 32, 16);
  k_transpose<<<gT, 256, 0, stream>>>(x, xT);
  k_prepw<<<1, 256, 0, stream>>>(coeffs, wsW);
  k_faces<<<GRID_F, 256, 0, stream>>>(xT, Gc, Gv, EW, NS, gf);
  k_verts<<<GRID_V, 256, 0, stream>>>(xT, Lc, Lv, Fc, Fv, gf, wsW, bias, out);
}

// Round 5
// 479.383 us; speedup vs baseline: 3.3094x; 3.3094x over previous
//
#include <hip/hip_runtime.h>
#include <hip/hip_bf16.h>

#define NVERT 40962
#define NFACE 81920
#define GRID_V ((NVERT + 3) / 4)      // 10241 blocks, 4 vertices/block (1/wave)
#define GRID_F (NFACE / 4)            // 20480 blocks, 4 faces/block (1/wave)

typedef unsigned int uint;
typedef __attribute__((ext_vector_type(4))) uint  uintx4;
typedef __attribute__((ext_vector_type(4))) float floatx4;
typedef __attribute__((ext_vector_type(8))) short shortx8;

// ---------- bf16 helpers (RNE) ----------
__device__ __forceinline__ uint packbf2(float a, float b) {
  uint ua = __float_as_uint(a); ua = ua + 0x7fffu + ((ua >> 16) & 1u);
  uint ub = __float_as_uint(b); ub = ub + 0x7fffu + ((ub >> 16) & 1u);
  return (ua >> 16) | (ub & 0xffff0000u);
}
__device__ __forceinline__ float2 unpackbf2(uint u) {
  float2 r;
  r.x = __uint_as_float(u << 16);
  r.y = __uint_as_float(u & 0xffff0000u);
  return r;
}
__device__ __forceinline__ short bfr(float x) {
  uint u = __float_as_uint(x);
  u = u + 0x7fffu + ((u >> 16) & 1u);
  return (short)(u >> 16);
}

// bijective XCD swizzle (m204)
__device__ __forceinline__ int swz(int blk, int nwg) {
  int q = nwg >> 3, r = nwg & 7;
  int xcd = blk & 7, idx = blk >> 3;
  return (xcd < r ? xcd * (q + 1) : r * (q + 1) + (xcd - r) * q) + idx;
}

// ---------- K0: transpose x[512,NV] f32 -> xT[NV,256] u32 (bf16x2), permuted --
__global__ __launch_bounds__(256) void k_transpose(const float* __restrict__ x,
                                                   uint* __restrict__ xT) {
  __shared__ float tile[32][33];
  int n0 = blockIdx.x * 32;
  int r0 = blockIdx.y * 32;
  int tx = threadIdx.x & 31;
  int ty = threadIdx.x >> 5;
#pragma unroll
  for (int i = 0; i < 32; i += 8) {
    int n = n0 + tx;
    tile[ty + i][tx] = (n < NVERT)
        ? __builtin_nontemporal_load(&x[(size_t)(r0 + ty + i) * NVERT + n]) : 0.f;
  }
  __syncthreads();
#pragma unroll
  for (int i = 0; i < 32; i += 16) {
    int nl = (threadIdx.x >> 4) + i;
    int u  = threadIdx.x & 15;
    int n  = n0 + nl;
    int ug = 16 * blockIdx.y + u;                       // global word index
    int up = (ug & 3) * 64 + (ug >> 4) * 4 + ((ug >> 2) & 3);
    if (n < NVERT)
      xT[(size_t)n * 256 + up] = packbf2(tile[2 * u][nl], tile[2 * u + 1][nl]);
  }
}

// ---------- K0b: pre-convert coeffs -> bf16 MFMA B-fragments ----------
__global__ __launch_bounds__(256) void k_prepw(const float* __restrict__ coeffs,
                                               short* __restrict__ wsW) {
  int t = threadIdx.x;
  int ks = t >> 6, lane = t & 63;
  int bm = lane & 15, h = lane >> 4;
  const float* wp0 = coeffs + (size_t)bm * 128 + 32 * ks + 8 * h;
  shortx8 f0, f1;
#pragma unroll
  for (int j = 0; j < 8; ++j) {
    f0[j] = bfr(wp0[j]);
    f1[j] = bfr(wp0[16 * 128 + j]);
  }
  *(shortx8*)(wsW + ((size_t)(ks * 2 + 0) * 64 + lane) * 8) = f0;
  *(shortx8*)(wsW + ((size_t)(ks * 2 + 1) * 64 + lane) * 8) = f1;
}

// ---------- K1: one wave per face -> gf[NF][512] (ew | ns), scalarized ------
__global__ __launch_bounds__(256) void k_faces(
    const uint* __restrict__ xT,
    const int* __restrict__ Gc, const float* __restrict__ Gv,
    const float* __restrict__ EW, const float* __restrict__ NS,
    uint* __restrict__ gf) {
  const int t = threadIdx.x, lane = t & 63;
  const int f = __builtin_amdgcn_readfirstlane(swz(blockIdx.x, GRID_F) * 4 + (t >> 6));
  const int voff = 4 * lane;

  float ea[4][2], sa[4][2];
#pragma unroll
  for (int ks = 0; ks < 4; ++ks) {
    ea[ks][0] = 0.f; ea[ks][1] = 0.f;
    sa[ks][0] = 0.f; sa[ks][1] = 0.f;
  }

#pragma unroll
  for (int comp = 0; comp < 3; ++comp) {
    const int base = comp * (3 * NFACE) + 3 * f;
    const float ewc = EW[3 * f + comp];      // scalar loads (uniform)
    const float nsc = NS[3 * f + comp];
#pragma unroll
    for (int j = 0; j < 3; ++j) {
      const int col = Gc[base + j];          // scalar load
      const float v = Gv[base + j];
      const float ve = v * ewc, vn = v * nsc;
      uintx4 g = *(const uintx4*)(xT + (size_t)col * 256 + voff);
#pragma unroll
      for (int ks = 0; ks < 4; ++ks) {
        float2 p = unpackbf2(g[ks]);
        ea[ks][0] = fmaf(ve, p.x, ea[ks][0]); ea[ks][1] = fmaf(ve, p.y, ea[ks][1]);
        sa[ks][0] = fmaf(vn, p.x, sa[ks][0]); sa[ks][1] = fmaf(vn, p.y, sa[ks][1]);
      }
    }
  }
  uintx4 we, wn;
#pragma unroll
  for (int ks = 0; ks < 4; ++ks) {
    we[ks] = packbf2(ea[ks][0], ea[ks][1]);
    wn[ks] = packbf2(sa[ks][0], sa[ks][1]);
  }
  uint* op = gf + (size_t)f * 512 + voff;
  *(uintx4*)op         = we;
  *(uintx4*)(op + 256) = wn;
}

// ---------- K2: one wave per vertex, scalarized indices, MFMA channel mix ----
__global__ __launch_bounds__(256) void k_verts(
    const uint* __restrict__ xT,
    const int* __restrict__ Lc, const float* __restrict__ Lv,
    const int* __restrict__ Fc, const float* __restrict__ Fv,
    const uint* __restrict__ gf,
    const short* __restrict__ wsW, const float* __restrict__ bias,
    float* __restrict__ out) {
  const int t = threadIdx.x, lane = t & 63;
  const int n = __builtin_amdgcn_readfirstlane(swz(blockIdx.x, GRID_V) * 4 + (t >> 6));
  if (n >= NVERT) return;
  const int h = lane >> 4, bm = lane & 15;
  const int voff = 4 * lane;

  // identity row
  uintx4 idw = *(const uintx4*)(xT + (size_t)n * 256 + voff);

  float lap[4][2];
#pragma unroll
  for (int ks = 0; ks < 4; ++ks) { lap[ks][0] = 0.f; lap[ks][1] = 0.f; }
#pragma unroll
  for (int j = 0; j < 7; ++j) {
    const int col = Lc[7 * n + j];           // scalar load
    const float v = Lv[7 * n + j];
    uintx4 g = *(const uintx4*)(xT + (size_t)col * 256 + voff);
#pragma unroll
    for (int ks = 0; ks < 4; ++ks) {
      float2 p = unpackbf2(g[ks]);
      lap[ks][0] = fmaf(v, p.x, lap[ks][0]);
      lap[ks][1] = fmaf(v, p.y, lap[ks][1]);
    }
  }

  float ea[4][2], na[4][2];
#pragma unroll
  for (int ks = 0; ks < 4; ++ks) {
    ea[ks][0] = 0.f; ea[ks][1] = 0.f;
    na[ks][0] = 0.f; na[ks][1] = 0.f;
  }
#pragma unroll
  for (int j = 0; j < 6; ++j) {
    const int fc = Fc[6 * n + j];            // scalar load
    const float v = Fv[6 * n + j];
    const uint* rp = gf + (size_t)fc * 512 + voff;
    uintx4 ge = *(const uintx4*)rp;
    uintx4 gn = *(const uintx4*)(rp + 256);
#pragma unroll
    for (int ks = 0; ks < 4; ++ks) {
      float2 a = unpackbf2(ge[ks]);
      float2 b = unpackbf2(gn[ks]);
      ea[ks][0] = fmaf(v, a.x, ea[ks][0]); ea[ks][1] = fmaf(v, a.y, ea[ks][1]);
      na[ks][0] = fmaf(v, b.x, na[ks][0]); na[ks][1] = fmaf(v, b.y, na[ks][1]);
    }
  }

  // A-fragments
  shortx8 afr[4];
#pragma unroll
  for (int ks = 0; ks < 4; ++ks) {
    float2 ip = unpackbf2(idw[ks]);
    shortx8 a;
    a[0] = bfr(ip.x);      a[1] = bfr(lap[ks][0]);
    a[2] = bfr(ea[ks][0]); a[3] = bfr(na[ks][0]);
    a[4] = bfr(ip.y);      a[5] = bfr(lap[ks][1]);
    a[6] = bfr(ea[ks][1]); a[7] = bfr(na[ks][1]);
    afr[ks] = a;
  }

  // MFMA with preconverted B-fragments
  float b0 = bias[bm], b1 = bias[16 + bm];
  floatx4 acc0 = {b0, b0, b0, b0};
  floatx4 acc1 = {b1, b1, b1, b1};
#pragma unroll
  for (int ks = 0; ks < 4; ++ks) {
    shortx8 bf0 = *(const shortx8*)(wsW + ((size_t)(ks * 2 + 0) * 64 + lane) * 8);
    acc0 = __builtin_amdgcn_mfma_f32_16x16x32_bf16(afr[ks], bf0, acc0, 0, 0, 0);
    shortx8 bf1 = *(const shortx8*)(wsW + ((size_t)(ks * 2 + 1) * 64 + lane) * 8);
    acc1 = __builtin_amdgcn_mfma_f32_16x16x32_bf16(afr[ks], bf1, acc1, 0, 0, 0);
  }

  // C/D layout: col = lane&15, row = (lane>>4)*4+reg; plain stores (L2 merges)
#pragma unroll
  for (int reg = 0; reg < 4; ++reg) {
    int b = h * 4 + reg;
    out[(size_t)(b * 32 + bm) * NVERT + n]      = acc0[reg];
    out[(size_t)(b * 32 + 16 + bm) * NVERT + n] = acc1[reg];
  }
}

extern "C" void kernel_launch(void* const* d_in, const int* in_sizes, int n_in,
                              void* d_out, int out_size, void* d_ws, size_t ws_size,
                              hipStream_t stream) {
  const float* x      = (const float*)d_in[0];
  const int*   Gc     = (const int*)  d_in[2];
  const float* Gv     = (const float*)d_in[3];
  const int*   Lc     = (const int*)  d_in[5];
  const float* Lv     = (const float*)d_in[6];
  const int*   Fc     = (const int*)  d_in[8];
  const float* Fv     = (const float*)d_in[9];
  const float* EW     = (const float*)d_in[10];
  const float* NS     = (const float*)d_in[11];
  const float* coeffs = (const float*)d_in[12];
  const float* bias   = (const float*)d_in[13];
  float* out = (float*)d_out;

  uint* xT  = (uint*)d_ws;                      // NVERT*256 u32
  uint* gf  = xT + (size_t)NVERT * 256;         // NFACE*512 u32 (ew|ns)
  short* wsW = (short*)(gf + (size_t)NFACE * 512);  // 4 KB of B-fragments

  dim3 gT((NVERT + 31) / 32, 16);
  k_transpose<<<gT, 256, 0, stream>>>(x, xT);
  k_prepw<<<1, 256, 0, stream>>>(coeffs, wsW);
  k_faces<<<GRID_F, 256, 0, stream>>>(xT, Gc, Gv, EW, NS, gf);
  k_verts<<<GRID_V, 256, 0, stream>>>(xT, Lc, Lv, Fc, Fv, gf, wsW, bias, out);
}